// Round 5
// baseline (245.395 us; speedup 1.0000x reference)
//
#include <hip/hip_runtime.h>
#include <hip/hip_bf16.h>
#include <hip/hip_cooperative_groups.h>

namespace cg = cooperative_groups;

#define VOCAB 50257
#define FEAT 512
#define NTOK (32 * 4096)
#define EPS 1e-12f
#define NFT 8                       // 64-wide feature tiles
#define NVT 786                     // ceil(VOCAB/64)
#define NTILES (NVT * NFT)          // 6288
#define NBLK 512
#define NTHR 512
#define NSG (NBLK * 2)              // 1024 subgroups (256 thr each)
#define P1_ITERS ((NTILES + NSG - 1) / NSG)   // 7
#define NWAVE (NBLK * (NTHR / 64))  // 4096 waves
#define P2_ITERS (NTOK / NWAVE)     // 32 exact

typedef float f32x4 __attribute__((ext_vector_type(4)));

__device__ __forceinline__ unsigned short f2bf(float x) {
    __hip_bfloat16 h = __float2bfloat16(x);  // RNE
    unsigned short u; __builtin_memcpy(&u, &h, 2); return u;
}
__device__ __forceinline__ float bfround(float x) {
    return __bfloat162float(__float2bfloat16(x));
}
__device__ __forceinline__ float bflo(unsigned int w) {
    unsigned int u = w << 16; float f; __builtin_memcpy(&f, &u, 4); return f;
}
__device__ __forceinline__ float bfhi(unsigned int w) {
    unsigned int u = w & 0xffff0000u; float f; __builtin_memcpy(&f, &u, 4); return f;
}

// ===========================================================================
// Fused cooperative kernel: transpose+bias+partials | inv table | gather+scale
// ===========================================================================
__global__ __launch_bounds__(NTHR, 4) void fused_encoder(
        const int* __restrict__ ids, const float* __restrict__ W,
        const float* __restrict__ b, unsigned short* __restrict__ Wt,
        float* __restrict__ partial, float* __restrict__ invn,
        float* __restrict__ out) {
    cg::grid_group grid = cg::this_grid();

    __shared__ float tile[2][64][65];
    __shared__ float psum[2][4][64];

    const int t   = threadIdx.x;        // 0..511
    const int sg  = t >> 8;             // subgroup 0/1
    const int st  = t & 255;            // subgroup-local tid
    const int l   = st & 63;            // lane
    const int w   = st >> 6;            // wave-in-subgroup 0..3
    const int c   = l & 15;             // v-group (4 v)
    const int r   = l >> 4;             // f-subrow 0..3
    const int gsg = blockIdx.x * 2 + sg;

    // ---------------- Phase 1: Wt + per-tile partial sums -----------------
    for (int i = 0; i < P1_ITERS; ++i) {
        const int tileIdx = gsg + i * NSG;
        const bool active = tileIdx < NTILES;
        const int vt = active ? (tileIdx >> 3) : 0;
        const int ft = active ? (tileIdx & 7) : 0;
        const int v0 = vt * 64, f0 = ft * 64;
        const int vb = v0 + c * 4;

        float p[4] = {0.f, 0.f, 0.f, 0.f};
        if (active) {
#pragma unroll
            for (int k = 0; k < 4; ++k) {
                const int fl = w * 16 + k * 4 + r;
                const int f  = f0 + fl;
                f32x4 x;
                if (vb + 3 < VOCAB) {
                    __builtin_memcpy(&x, W + (size_t)f * VOCAB + vb, 16);
                } else {
#pragma unroll
                    for (int q = 0; q < 4; ++q)
                        x[q] = (vb + q < VOCAB) ? W[(size_t)f * VOCAB + vb + q] : 0.0f;
                }
                const float bf = b[f];
#pragma unroll
                for (int q = 0; q < 4; ++q) {
                    const float xi = x[q] + bf;
                    tile[sg][fl][c * 4 + q] = xi;
                    const float xr = bfround(xi);
                    p[q] += xr * xr;
                }
            }
        }
        // reduce across the 4 f-subrow groups (lanes l, l^16, l^32, l^48)
#pragma unroll
        for (int q = 0; q < 4; ++q) {
            float s = p[q];
            s += __shfl_xor(s, 16, 64);
            s += __shfl_xor(s, 32, 64);
            if (r == 0) psum[sg][w][c * 4 + q] = s;
        }
        __syncthreads();   // tile+psum writes -> reads

        if (active && st < 64) {
            const int v = v0 + st;
            if (v < VOCAB)
                partial[ft * VOCAB + v] =
                    psum[sg][0][st] + psum[sg][1][st] + psum[sg][2][st] + psum[sg][3][st];
        }
        if (active) {
#pragma unroll
            for (int ps = 0; ps < 2; ++ps) {
                const int idx = st + 256 * ps;
                const int vl  = idx >> 3;
                const int ch  = idx & 7;
                const int v   = v0 + vl;
                if (v < VOCAB) {
                    unsigned int pk[4];
#pragma unroll
                    for (int j = 0; j < 4; ++j) {
                        const int f = ch * 8 + 2 * j;
                        pk[j] = (unsigned int)f2bf(tile[sg][f][vl]) |
                                ((unsigned int)f2bf(tile[sg][f + 1][vl]) << 16);
                    }
                    *(uint4*)(Wt + (size_t)v * FEAT + f0 + ch * 8) =
                        make_uint4(pk[0], pk[1], pk[2], pk[3]);
                }
            }
        }
        __syncthreads();   // tile reads (iter i) -> tile writes (iter i+1)
    }

    grid.sync();

    // ---------------- Phase 1b: inv-norm table ----------------------------
    {
        const int v = blockIdx.x * NTHR + t;
        if (v < VOCAB) {
            float s = 0.0f;
#pragma unroll
            for (int j = 0; j < NFT; ++j) s += partial[j * VOCAB + v];
            invn[v] = 1.0f / fmaxf(sqrtf(s), EPS);
        }
    }

    grid.sync();

    // ---------------- Phase 2: pipelined gather + scale + NT store --------
    {
        const int gw = blockIdx.x * (NTHR / 64) + (t >> 6);   // 0..4095

        int   id = ids[gw];
        uint4 rr = *((const uint4*)(Wt + (size_t)id * FEAT) + l);
        float iv = invn[id];

#pragma unroll 1
        for (int it = 0; it < P2_ITERS; ++it) {
            const bool more = it + 1 < P2_ITERS;
            const int   idn = more ? ids[(it + 1) * NWAVE + gw] : 0;
            const uint4 rn  = *((const uint4*)(Wt + (size_t)idn * FEAT) + l);
            const float ivn = invn[idn];

            float x[8];
            x[0] = bflo(rr.x); x[1] = bfhi(rr.x);
            x[2] = bflo(rr.y); x[3] = bfhi(rr.y);
            x[4] = bflo(rr.z); x[5] = bfhi(rr.z);
            x[6] = bflo(rr.w); x[7] = bfhi(rr.w);

            f32x4 o0 = {x[0] * iv, x[1] * iv, x[2] * iv, x[3] * iv};
            f32x4 o1 = {x[4] * iv, x[5] * iv, x[6] * iv, x[7] * iv};
            f32x4* dst = (f32x4*)(out + (size_t)(it * NWAVE + gw) * FEAT + l * 8);
            __builtin_nontemporal_store(o0, dst);
            __builtin_nontemporal_store(o1, dst + 1);

            rr = rn; iv = ivn;
        }
    }
}

// ===========================================================================
// Fallback path (non-cooperative): R4's 3-kernel pipeline
// ===========================================================================
__global__ __launch_bounds__(256) void transpose_bias_bf16(
        const float* __restrict__ W, const float* __restrict__ b,
        unsigned short* __restrict__ Wt, float* __restrict__ partial) {
    __shared__ float tile[64][65];
    __shared__ float psum[4][64];
    const int t = threadIdx.x, l = t & 63, w = t >> 6;
    const int v0 = blockIdx.x * 64, f0 = blockIdx.y * 64;
    const int c = l & 15, r = l >> 4;
    const int vb = v0 + c * 4;

    float p[4] = {0.f, 0.f, 0.f, 0.f};
#pragma unroll
    for (int k = 0; k < 4; ++k) {
        const int fl = w * 16 + k * 4 + r;
        const int f  = f0 + fl;
        f32x4 x;
        if (vb + 3 < VOCAB) {
            __builtin_memcpy(&x, W + (size_t)f * VOCAB + vb, 16);
        } else {
#pragma unroll
            for (int q = 0; q < 4; ++q)
                x[q] = (vb + q < VOCAB) ? W[(size_t)f * VOCAB + vb + q] : 0.0f;
        }
        const float bf = b[f];
#pragma unroll
        for (int q = 0; q < 4; ++q) {
            const float xi = x[q] + bf;
            tile[fl][c * 4 + q] = xi;
            const float xr = bfround(xi);
            p[q] += xr * xr;
        }
    }
#pragma unroll
    for (int q = 0; q < 4; ++q) {
        float s = p[q];
        s += __shfl_xor(s, 16, 64);
        s += __shfl_xor(s, 32, 64);
        if (r == 0) psum[w][c * 4 + q] = s;
    }
    __syncthreads();
    if (t < 64) {
        const int v = v0 + t;
        if (v < VOCAB)
            partial[blockIdx.y * VOCAB + v] =
                psum[0][t] + psum[1][t] + psum[2][t] + psum[3][t];
    }
#pragma unroll
    for (int ps = 0; ps < 2; ++ps) {
        const int idx = t + 256 * ps;
        const int vl = idx >> 3, ch = idx & 7;
        const int v = v0 + vl;
        if (v < VOCAB) {
            unsigned int pk[4];
#pragma unroll
            for (int j = 0; j < 4; ++j) {
                const int f = ch * 8 + 2 * j;
                pk[j] = (unsigned int)f2bf(tile[f][vl]) |
                        ((unsigned int)f2bf(tile[f + 1][vl]) << 16);
            }
            *(uint4*)(Wt + (size_t)v * FEAT + f0 + ch * 8) =
                make_uint4(pk[0], pk[1], pk[2], pk[3]);
        }
    }
}

__global__ __launch_bounds__(256) void norm_table(const float* __restrict__ partial,
                                                  float* __restrict__ invn) {
    const int v = blockIdx.x * 256 + threadIdx.x;
    if (v >= VOCAB) return;
    float s = 0.0f;
#pragma unroll
    for (int j = 0; j < NFT; ++j) s += partial[j * VOCAB + v];
    invn[v] = 1.0f / fmaxf(sqrtf(s), EPS);
}

__global__ __launch_bounds__(256) void encode_bf16(
        const int* __restrict__ ids, const unsigned short* __restrict__ Wt,
        const float* __restrict__ invn, float* __restrict__ out) {
    const int tok  = (int)((blockIdx.x * (unsigned long long)blockDim.x + threadIdx.x) >> 6);
    const int lane = threadIdx.x & 63;
    if (tok >= NTOK) return;
    const int id = ids[tok];
    const uint4 rr = *((const uint4*)(Wt + (size_t)id * FEAT) + lane);
    const float inv = invn[id];
    float x[8];
    x[0] = bflo(rr.x); x[1] = bfhi(rr.x);
    x[2] = bflo(rr.y); x[3] = bfhi(rr.y);
    x[4] = bflo(rr.z); x[5] = bfhi(rr.z);
    x[6] = bflo(rr.w); x[7] = bfhi(rr.w);
    f32x4 o0 = {x[0] * inv, x[1] * inv, x[2] * inv, x[3] * inv};
    f32x4 o1 = {x[4] * inv, x[5] * inv, x[6] * inv, x[7] * inv};
    f32x4* dst = (f32x4*)(out + (size_t)tok * FEAT + lane * 8);
    __builtin_nontemporal_store(o0, dst);
    __builtin_nontemporal_store(o1, dst + 1);
}

__global__ __launch_bounds__(256) void encode_direct(const int* __restrict__ ids,
                                                     const float* __restrict__ W,
                                                     const float* __restrict__ bias,
                                                     float* __restrict__ out) {
    const int tok  = (int)((blockIdx.x * (unsigned long long)blockDim.x + threadIdx.x) >> 6);
    const int lane = threadIdx.x & 63;
    if (tok >= NTOK) return;
    const int id = ids[tok];
    float x[8];
    float s = 0.0f;
#pragma unroll
    for (int j = 0; j < 8; ++j) {
        const int f = lane * 8 + j;
        x[j] = W[(size_t)f * VOCAB + id] + bias[f];
        s += x[j] * x[j];
    }
#pragma unroll
    for (int off = 32; off > 0; off >>= 1)
        s += __shfl_xor(s, off, 64);
    const float inv = 1.0f / fmaxf(sqrtf(s), EPS);
    float4 o0 = make_float4(x[0] * inv, x[1] * inv, x[2] * inv, x[3] * inv);
    float4 o1 = make_float4(x[4] * inv, x[5] * inv, x[6] * inv, x[7] * inv);
    float4* dst = (float4*)(out + (size_t)tok * FEAT + lane * 8);
    dst[0] = o0;
    dst[1] = o1;
}

extern "C" void kernel_launch(void* const* d_in, const int* in_sizes, int n_in,
                              void* d_out, int out_size, void* d_ws, size_t ws_size,
                              hipStream_t stream) {
    const int*   ids  = (const int*)d_in[0];
    const float* W    = (const float*)d_in[1];
    const float* bias = (const float*)d_in[2];
    float*       out  = (float*)d_out;

    const size_t wt_bytes   = (size_t)VOCAB * FEAT * sizeof(unsigned short); // 51.46 MB
    const size_t part_bytes = (size_t)NFT * VOCAB * sizeof(float);           // 1.6 MB
    const size_t inv_bytes  = (size_t)VOCAB * sizeof(float);                 // 0.2 MB

    if (ws_size >= wt_bytes + part_bytes + inv_bytes) {
        unsigned short* Wt = (unsigned short*)d_ws;
        float* partial     = (float*)((char*)d_ws + wt_bytes);
        float* invn        = (float*)((char*)d_ws + wt_bytes + part_bytes);

        void* args[] = {(void*)&ids, (void*)&W, (void*)&bias,
                        (void*)&Wt, (void*)&partial, (void*)&invn, (void*)&out};
        hipError_t err = hipLaunchCooperativeKernel(
            (const void*)fused_encoder, dim3(NBLK), dim3(NTHR), args, 0, stream);
        if (err != hipSuccess) {
            // fallback: 3-kernel pipeline (also used if coop capture unsupported)
            dim3 tgrid((VOCAB + 63) / 64, FEAT / 64);
            transpose_bias_bf16<<<tgrid, 256, 0, stream>>>(W, bias, Wt, partial);
            norm_table<<<(VOCAB + 255) / 256, 256, 0, stream>>>(partial, invn);
            encode_bf16<<<NTOK / 4, 256, 0, stream>>>(ids, Wt, invn, out);
        }
    } else {
        encode_direct<<<NTOK / 4, 256, 0, stream>>>(ids, W, bias, out);
    }
}